// Round 1
// baseline (164.786 us; speedup 1.0000x reference)
//
#include <hip/hip_runtime.h>
#include <math.h>

#define G_GRAPHS 4096
#define NPG 32
#define E_EDGES 1048576
#define S_DIM 64
#define H_DIM 128
#define CAP 128
#define NEG_SLOPE 0.2f

// ws layout (4-byte units):
//   cnt      : 2*G_GRAPHS ints        (branch-major: up then down)
//   buckets  : 2*G_GRAPHS*CAP ints    (src node indices per (branch,graph))
//   wvec     : 4*64 floats            (wsrc_up, wdst_up, wsrc_dn, wdst_dn)

__global__ void init_kernel(int* __restrict__ cnt, float* __restrict__ wvec,
                            const float* __restrict__ upW, const float* __restrict__ upAs,
                            const float* __restrict__ upAd,
                            const float* __restrict__ dnW, const float* __restrict__ dnAs,
                            const float* __restrict__ dnAd) {
    int t = threadIdx.x;  // 256 threads, 1 block
    for (int i = t; i < 2 * G_GRAPHS; i += 256) cnt[i] = 0;
    // wvec[v][s] = sum_h W[s][h] * att[h]
    int vec = t >> 6;   // 0..3
    int s   = t & 63;
    const float* W   = (vec < 2) ? upW : dnW;
    const float* att = (vec == 0) ? upAs : (vec == 1) ? upAd : (vec == 2) ? dnAs : dnAd;
    float acc = 0.f;
    for (int h = 0; h < H_DIM; ++h) acc += W[s * H_DIM + h] * att[h];
    wvec[vec * 64 + s] = acc;
}

__global__ void scan_kernel(const int* __restrict__ up_ei, const int* __restrict__ dn_ei,
                            int* __restrict__ cnt, int* __restrict__ buckets) {
    unsigned tid = blockIdx.x * blockDim.x + threadIdx.x;   // 0 .. 2E-1 exactly
    int branch = (tid >= E_EDGES) ? 1 : 0;
    unsigned e = branch ? (tid - E_EDGES) : tid;
    const int* ei = branch ? dn_ei : up_ei;
    int dst = ei[E_EDGES + e];          // row 1 = dst
    if ((dst & (NPG - 1)) == NPG - 1) { // only last-node-of-graph dsts matter
        int g = dst >> 5;
        int pos = atomicAdd(cnt + branch * G_GRAPHS + g, 1);
        if (pos < CAP) {
            int src = ei[e];            // row 0 = src
            buckets[(branch * G_GRAPHS + g) * CAP + pos] = src;
        }
    }
}

__global__ __launch_bounds__(128) void gat_kernel(
        const float* __restrict__ up_x, const float* __restrict__ dn_x,
        const float* __restrict__ upW, const float* __restrict__ dnW,
        const float* __restrict__ up_bias, const float* __restrict__ dn_bias,
        const float* __restrict__ mlp_W, const float* __restrict__ mlp_b,
        const int* __restrict__ cnt, const int* __restrict__ buckets,
        const float* __restrict__ wvec, float* __restrict__ out) {
    int g    = blockIdx.x;
    int wave = threadIdx.x >> 6;   // 0 = up branch, 1 = down branch
    int lane = threadIdx.x & 63;

    __shared__ float evals[2][CAP];
    __shared__ float xsum_s[2][S_DIM];
    __shared__ float bout[2][H_DIM];

    const float* x    = wave ? dn_x : up_x;
    const float* W    = wave ? dnW : upW;
    const float* bias = wave ? dn_bias : up_bias;
    const float* wsrc = wvec + wave * 128;
    const float* wdst = wsrc + 64;

    int d = g * NPG + (NPG - 1);   // self node (last node of graph g)

    // a_dst = x[d] . wdst  (64-lane dot + butterfly reduce; result in all lanes)
    float v = x[d * S_DIM + lane] * wdst[lane];
    #pragma unroll
    for (int m = 32; m; m >>= 1) v += __shfl_xor(v, m, 64);
    float a_dst = v;

    int k = cnt[wave * G_GRAPHS + g];
    if (k > CAP) k = CAP;
    const int* bk = buckets + (wave * G_GRAPHS + g) * CAP;

    // pass A: logits + running max (identical in all lanes)
    float mmax = -INFINITY;
    for (int i = 0; i < k; ++i) {
        int src = bk[i];
        float t = x[src * S_DIM + lane] * wsrc[lane];
        #pragma unroll
        for (int m = 32; m; m >>= 1) t += __shfl_xor(t, m, 64);
        float e = t + a_dst;
        e = (e > 0.f) ? e : NEG_SLOPE * e;
        if (lane == 0) evals[wave][i] = e;
        if (e > mmax) mmax = e;
    }

    // pass B: softmax-weighted sum of x rows (lane holds component `lane`)
    float denom = 0.f, xs = 0.f;
    for (int i = 0; i < k; ++i) {
        float p = __expf(evals[wave][i] - mmax);
        int src = bk[i];
        xs += p * x[src * S_DIM + lane];
        denom += p;
    }
    xs /= (denom + 1e-16f);
    xsum_s[wave][lane] = xs;   // same-wave LDS: no barrier needed

    // out_h = xsum @ W + bias, then sigmoid. lane covers h=lane and h=lane+64
    float o0 = bias[lane], o1 = bias[lane + 64];
    for (int s = 0; s < S_DIM; ++s) {
        float xv = xsum_s[wave][s];
        o0 += xv * W[s * H_DIM + lane];
        o1 += xv * W[s * H_DIM + lane + 64];
    }
    o0 = 1.f / (1.f + __expf(-o0));
    o1 = 1.f / (1.f + __expf(-o1));
    bout[wave][lane]      = o0;
    bout[wave][lane + 64] = o1;
    __syncthreads();

    // final: out[g] = sum_h up[h]*dn[h]*mlpW[h] + mlp_b
    if (wave == 0) {
        float part = bout[0][lane] * bout[1][lane] * mlp_W[lane]
                   + bout[0][lane + 64] * bout[1][lane + 64] * mlp_W[lane + 64];
        #pragma unroll
        for (int m = 32; m; m >>= 1) part += __shfl_xor(part, m, 64);
        if (lane == 0) out[g] = part + mlp_b[0];
    }
}

extern "C" void kernel_launch(void* const* d_in, const int* in_sizes, int n_in,
                              void* d_out, int out_size, void* d_ws, size_t ws_size,
                              hipStream_t stream) {
    const float* up_x  = (const float*)d_in[0];
    const int*   up_ei = (const int*)d_in[1];
    // d_in[2] = up_batch (unused: NPG fixed -> self_idx = 32g+31)
    const float* dn_x  = (const float*)d_in[3];
    const int*   dn_ei = (const int*)d_in[4];
    // d_in[5] = down_batch (unused)
    const float* upW   = (const float*)d_in[6];
    const float* upAs  = (const float*)d_in[7];
    const float* upAd  = (const float*)d_in[8];
    const float* upB   = (const float*)d_in[9];
    const float* dnW   = (const float*)d_in[10];
    const float* dnAs  = (const float*)d_in[11];
    const float* dnAd  = (const float*)d_in[12];
    const float* dnB   = (const float*)d_in[13];
    const float* mlpW  = (const float*)d_in[14];
    const float* mlpB  = (const float*)d_in[15];
    float* out = (float*)d_out;

    int*   cnt     = (int*)d_ws;
    int*   buckets = cnt + 2 * G_GRAPHS;
    float* wvec    = (float*)(buckets + 2 * G_GRAPHS * CAP);

    init_kernel<<<1, 256, 0, stream>>>(cnt, wvec, upW, upAs, upAd, dnW, dnAs, dnAd);
    scan_kernel<<<(2 * E_EDGES) / 256, 256, 0, stream>>>(up_ei, dn_ei, cnt, buckets);
    gat_kernel<<<G_GRAPHS, 128, 0, stream>>>(up_x, dn_x, upW, dnW, upB, dnB,
                                             mlpW, mlpB, cnt, buckets, wvec, out);
}

// Round 2
// 155.368 us; speedup vs baseline: 1.0606x; 1.0606x over previous
//
#include <hip/hip_runtime.h>
#include <math.h>

#define G_GRAPHS 4096
#define NPG 32
#define E_EDGES 1048576
#define S_DIM 64
#define H_DIM 128
#define CAP 128
#define MAXIT 8          // register-cached edge slots per 16-lane group (covers k<=32)
#define NEG_SLOPE 0.2f

// ws layout (4-byte units):
//   cnt      : 2*G_GRAPHS ints        (branch-major: up then down)
//   buckets  : 2*G_GRAPHS*CAP ints    (src node indices per (branch,graph))
//   wvec     : 4*64 floats            (wsrc_up, wdst_up, wsrc_dn, wdst_dn)

__global__ __launch_bounds__(256) void init_kernel(
        int* __restrict__ cnt, float* __restrict__ wvec,
        const float* __restrict__ upW, const float* __restrict__ upAs,
        const float* __restrict__ upAd,
        const float* __restrict__ dnW, const float* __restrict__ dnAs,
        const float* __restrict__ dnAd) {
    int t = threadIdx.x;  // 256 threads, 1 block
    for (int i = t; i < 2 * G_GRAPHS; i += 256) cnt[i] = 0;
    // wvec[v][s] = sum_h W[s][h] * att[h], fully unrolled float4
    int vec = t >> 6;   // 0..3
    int s   = t & 63;
    const float* W   = (vec < 2) ? upW : dnW;
    const float* att = (vec == 0) ? upAs : (vec == 1) ? upAd : (vec == 2) ? dnAs : dnAd;
    const float4* Wr = (const float4*)(W + s * H_DIM);
    const float4* A4 = (const float4*)att;
    float a0 = 0.f, a1 = 0.f, a2 = 0.f, a3 = 0.f;
    #pragma unroll
    for (int h = 0; h < H_DIM / 4; ++h) {
        float4 w = Wr[h], a = A4[h];
        a0 += w.x * a.x; a1 += w.y * a.y; a2 += w.z * a.z; a3 += w.w * a.w;
    }
    wvec[vec * 64 + s] = (a0 + a1) + (a2 + a3);
}

__global__ __launch_bounds__(256) void scan_kernel(
        const int* __restrict__ up_ei, const int* __restrict__ dn_ei,
        int* __restrict__ cnt, int* __restrict__ buckets) {
    int branch = blockIdx.y;
    const int* ei = branch ? dn_ei : up_ei;
    unsigned e4 = blockIdx.x * 256u + threadIdx.x;       // 0 .. E/4-1
    int4 d4 = ((const int4*)(ei + E_EDGES))[e4];         // 4 dst values, 16B/lane
    int* bcnt  = cnt + branch * G_GRAPHS;
    int* bbase = buckets + branch * G_GRAPHS * CAP;
    unsigned e0 = e4 * 4u;
    int ds[4] = {d4.x, d4.y, d4.z, d4.w};
    #pragma unroll
    for (int j = 0; j < 4; ++j) {
        int dst = ds[j];
        if ((dst & (NPG - 1)) == NPG - 1) {   // only last-node-of-graph dsts matter
            int g = dst >> 5;
            int pos = atomicAdd(bcnt + g, 1);
            if (pos < CAP) bbase[g * CAP + pos] = ei[e0 + j];
        }
    }
}

__global__ __launch_bounds__(128) void gat_kernel(
        const float* __restrict__ up_x, const float* __restrict__ dn_x,
        const float* __restrict__ upW, const float* __restrict__ dnW,
        const float* __restrict__ up_bias, const float* __restrict__ dn_bias,
        const float* __restrict__ mlp_W, const float* __restrict__ mlp_b,
        const int* __restrict__ cnt, const int* __restrict__ buckets,
        const float* __restrict__ wvec, float* __restrict__ out) {
    int g    = blockIdx.x;
    int wave = threadIdx.x >> 6;   // 0 = up branch, 1 = down branch
    int lane = threadIdx.x & 63;
    int q    = lane >> 4;          // edge-slot group 0..3
    int t    = lane & 15;          // float4 chunk index within a row

    __shared__ float evals[2][CAP];      // logits, then probs
    __shared__ float xsum_s[2][S_DIM];
    __shared__ float bout[2][H_DIM];

    const float*  x    = wave ? dn_x : up_x;
    const float4* x4   = (const float4*)x;
    const float*  W    = wave ? dnW : upW;
    const float*  bias = wave ? dn_bias : up_bias;
    const float*  wsrc = wvec + wave * 128;
    const float4  ws4  = ((const float4*)wsrc)[t];
    const float4  wd4  = ((const float4*)(wsrc + 64))[t];

    int d = g * NPG + (NPG - 1);   // self node (last node of graph g)

    // a_dst = x[d].wdst — 16-lane grouped dot (redundant across groups, same $line)
    float4 xd = x4[d * 16 + t];
    float ad = xd.x * wd4.x + xd.y * wd4.y + xd.z * wd4.z + xd.w * wd4.w;
    #pragma unroll
    for (int m = 1; m < 16; m <<= 1) ad += __shfl_xor(ad, m, 64);

    int k = cnt[wave * G_GRAPHS + g];
    if (k > CAP) k = CAP;
    const int* bk = buckets + (wave * G_GRAPHS + g) * CAP;
    int kk = (k + 3) >> 2;         // group-iterations: 4 edges per iteration

    float4 rows[MAXIT];
    // phase 1: logits, 4 edges in parallel, rows cached in registers
    #pragma unroll
    for (int it = 0; it < MAXIT; ++it) {
        if (it >= kk) break;
        int i = it * 4 + q;
        bool valid = (i < k);
        int src = bk[valid ? i : 0];
        float4 xr = x4[src * 16 + t];
        rows[it] = xr;
        float e = xr.x * ws4.x + xr.y * ws4.y + xr.z * ws4.z + xr.w * ws4.w;
        #pragma unroll
        for (int m = 1; m < 16; m <<= 1) e += __shfl_xor(e, m, 64);
        e += ad;
        e = (e > 0.f) ? e : NEG_SLOPE * e;
        if (valid && t == 0) evals[wave][i] = e;
    }
    for (int it = MAXIT; it < kk; ++it) {    // rare tail (k > 32)
        int i = it * 4 + q;
        bool valid = (i < k);
        int src = bk[valid ? i : 0];
        float4 xr = x4[src * 16 + t];
        float e = xr.x * ws4.x + xr.y * ws4.y + xr.z * ws4.z + xr.w * ws4.w;
        #pragma unroll
        for (int m = 1; m < 16; m <<= 1) e += __shfl_xor(e, m, 64);
        e += ad;
        e = (e > 0.f) ? e : NEG_SLOPE * e;
        if (valid && t == 0) evals[wave][i] = e;
    }

    // softmax max + denom (lane-strided over k; wave-synchronous LDS)
    float mmax = -INFINITY;
    for (int i = lane; i < k; i += 64) mmax = fmaxf(mmax, evals[wave][i]);
    #pragma unroll
    for (int m = 32; m; m >>= 1) mmax = fmaxf(mmax, __shfl_xor(mmax, m, 64));
    float denom = 0.f;
    for (int i = lane; i < k; i += 64) {
        float p = __expf(evals[wave][i] - mmax);
        evals[wave][i] = p;                 // store prob in place
        denom += p;
    }
    #pragma unroll
    for (int m = 32; m; m >>= 1) denom += __shfl_xor(denom, m, 64);
    float inv = 1.f / (denom + 1e-16f);

    // phase 2: weighted row sum from register cache
    float4 acc = {0.f, 0.f, 0.f, 0.f};
    #pragma unroll
    for (int it = 0; it < MAXIT; ++it) {
        if (it >= kk) break;
        int i = it * 4 + q;
        float p = (i < k) ? evals[wave][i] : 0.f;
        float4 xr = rows[it];
        acc.x += p * xr.x; acc.y += p * xr.y; acc.z += p * xr.z; acc.w += p * xr.w;
    }
    for (int it = MAXIT; it < kk; ++it) {    // rare tail re-gathers
        int i = it * 4 + q;
        bool valid = (i < k);
        float p = valid ? evals[wave][i] : 0.f;
        int src = bk[valid ? i : 0];
        float4 xr = x4[src * 16 + t];
        acc.x += p * xr.x; acc.y += p * xr.y; acc.z += p * xr.z; acc.w += p * xr.w;
    }
    // combine the 4 edge-slot groups
    #pragma unroll
    for (int m = 16; m < 64; m <<= 1) {
        acc.x += __shfl_xor(acc.x, m, 64);
        acc.y += __shfl_xor(acc.y, m, 64);
        acc.z += __shfl_xor(acc.z, m, 64);
        acc.w += __shfl_xor(acc.w, m, 64);
    }
    if (lane < 16) {
        float4 xs = {acc.x * inv, acc.y * inv, acc.z * inv, acc.w * inv};
        ((float4*)xsum_s[wave])[lane] = xs;
    }

    // out_h = xsum @ W + bias, sigmoid; lane covers h=2*lane, 2*lane+1 (float2 W)
    const float2* W2 = (const float2*)W;
    float2 bb = ((const float2*)bias)[lane];
    float o0 = bb.x, o1 = bb.y;
    #pragma unroll 8
    for (int s = 0; s < S_DIM; ++s) {
        float xv = xsum_s[wave][s];
        float2 w = W2[s * 64 + lane];
        o0 += xv * w.x;
        o1 += xv * w.y;
    }
    o0 = 1.f / (1.f + __expf(-o0));
    o1 = 1.f / (1.f + __expf(-o1));
    bout[wave][2 * lane]     = o0;
    bout[wave][2 * lane + 1] = o1;
    __syncthreads();

    // final: out[g] = sum_h up[h]*dn[h]*mlpW[h] + mlp_b
    if (wave == 0) {
        float2 u  = ((const float2*)bout[0])[lane];
        float2 dn = ((const float2*)bout[1])[lane];
        float2 mw = ((const float2*)mlp_W)[lane];
        float part = u.x * dn.x * mw.x + u.y * dn.y * mw.y;
        #pragma unroll
        for (int m = 32; m; m >>= 1) part += __shfl_xor(part, m, 64);
        if (lane == 0) out[g] = part + mlp_b[0];
    }
}

extern "C" void kernel_launch(void* const* d_in, const int* in_sizes, int n_in,
                              void* d_out, int out_size, void* d_ws, size_t ws_size,
                              hipStream_t stream) {
    const float* up_x  = (const float*)d_in[0];
    const int*   up_ei = (const int*)d_in[1];
    // d_in[2] = up_batch (unused: NPG fixed -> self_idx = 32g+31)
    const float* dn_x  = (const float*)d_in[3];
    const int*   dn_ei = (const int*)d_in[4];
    // d_in[5] = down_batch (unused)
    const float* upW   = (const float*)d_in[6];
    const float* upAs  = (const float*)d_in[7];
    const float* upAd  = (const float*)d_in[8];
    const float* upB   = (const float*)d_in[9];
    const float* dnW   = (const float*)d_in[10];
    const float* dnAs  = (const float*)d_in[11];
    const float* dnAd  = (const float*)d_in[12];
    const float* dnB   = (const float*)d_in[13];
    const float* mlpW  = (const float*)d_in[14];
    const float* mlpB  = (const float*)d_in[15];
    float* out = (float*)d_out;

    int*   cnt     = (int*)d_ws;
    int*   buckets = cnt + 2 * G_GRAPHS;
    float* wvec    = (float*)(buckets + 2 * G_GRAPHS * CAP);

    init_kernel<<<1, 256, 0, stream>>>(cnt, wvec, upW, upAs, upAd, dnW, dnAs, dnAd);
    scan_kernel<<<dim3(E_EDGES / 4 / 256, 2), 256, 0, stream>>>(up_ei, dn_ei, cnt, buckets);
    gat_kernel<<<G_GRAPHS, 128, 0, stream>>>(up_x, dn_x, upW, dnW, upB, dnB,
                                             mlpW, mlpB, cnt, buckets, wvec, out);
}